// Round 11
// baseline (536.815 us; speedup 1.0000x reference)
//
#include <hip/hip_runtime.h>
#include <math.h>

#define BB 4
#define SS 4096
#define DD 2048
#define EE 64
#define KK 8
#define TT_TOTAL (BB*SS)      // 16384 tokens
#define E2 128                // stacked outputs (Wr 0..63, Wn 64..127)
#define DK 32
#define NC (DD/DK)
#define DELTA 1e-4f           // flag threshold: >=8x worst-case f32 z error

typedef double double2_t __attribute__((ext_vector_type(2)));

__device__ __forceinline__ double softplus64(double x) {
    return fmax(x, 0.0) + log1p(exp(-fabs(x)));
}
__device__ __forceinline__ float softplus32(float x) {
    return fmaxf(x, 0.0f) + log1pf(expf(-fabsf(x)));
}

// =====================================================================
// f32 GEMM: block 128 tok x 128 out, thread tile 8x8 (R9-verified
// conflict-free layout), f32 LDS + f32 FMA (no cvt). acc = 64 VGPR ->
// 4 blocks/CU at KS=8 (grid 1024). zp partials in f32.
// =====================================================================
#define ROWF 132   // 128 cols + 4 pad floats (528 B rows, 16B-aligned)

template<int KS>
__launch_bounds__(256, 4)
__global__ void gemmf32_kernel(const float* __restrict__ x,
                               const float* __restrict__ Wr,
                               const float* __restrict__ Wn,
                               float* __restrict__ zp)
{
    __shared__ __align__(16) float xs[DK][ROWF];   // 16896 B
    __shared__ __align__(16) float ws[DK][ROWF];   // 16896 B

    const int tid   = threadIdx.x;
    const int split = blockIdx.x % KS;
    const int bt    = blockIdx.x / KS;
    const int tok0  = bt * 128;
    const int kbase = split * (DD / KS);
    const int NCH   = (DD / KS) / DK;

    const int srow = tid & 127;
    const int skh  = tid >> 7;            // 0/1 -> k 0..15 / 16..31
    const float* xsrc = x + (size_t)(tok0 + srow) * DD + kbase + 16 * skh;
    const float* wsrc = ((srow < EE) ? Wr + (size_t)srow * DD
                                     : Wn + (size_t)(srow - EE) * DD)
                        + kbase + 16 * skh;

    const int og2 = tid & 15;
    const int tg2 = tid >> 4;

    float acc[8][8];
    #pragma unroll
    for (int t = 0; t < 8; ++t)
        #pragma unroll
        for (int o = 0; o < 8; ++o) acc[t][o] = 0.0f;

    float4 xa[4], wa[4];
    #pragma unroll
    for (int i = 0; i < 4; ++i) {
        xa[i] = *reinterpret_cast<const float4*>(xsrc + 4 * i);
        wa[i] = *reinterpret_cast<const float4*>(wsrc + 4 * i);
    }

    for (int c = 0; c < NCH; ++c) {
        __syncthreads();
        {
            const int k0 = 16 * skh;
            #pragma unroll
            for (int i = 0; i < 4; ++i) {
                xs[k0 + 4*i + 0][srow] = xa[i].x;
                xs[k0 + 4*i + 1][srow] = xa[i].y;
                xs[k0 + 4*i + 2][srow] = xa[i].z;
                xs[k0 + 4*i + 3][srow] = xa[i].w;
                ws[k0 + 4*i + 0][srow] = wa[i].x;
                ws[k0 + 4*i + 1][srow] = wa[i].y;
                ws[k0 + 4*i + 2][srow] = wa[i].z;
                ws[k0 + 4*i + 3][srow] = wa[i].w;
            }
        }
        __syncthreads();

        if (c + 1 < NCH) {
            const int off = (c + 1) * DK;
            #pragma unroll
            for (int i = 0; i < 4; ++i) {
                xa[i] = *reinterpret_cast<const float4*>(xsrc + off + 4 * i);
                wa[i] = *reinterpret_cast<const float4*>(wsrc + off + 4 * i);
            }
        }

        #pragma unroll 4
        for (int k = 0; k < DK; ++k) {
            const float4 fx0 = *reinterpret_cast<const float4*>(&xs[k][4 * tg2]);
            const float4 fx1 = *reinterpret_cast<const float4*>(&xs[k][64 + 4 * tg2]);
            const float4 fw0 = *reinterpret_cast<const float4*>(&ws[k][4 * og2]);
            const float4 fw1 = *reinterpret_cast<const float4*>(&ws[k][64 + 4 * og2]);
            const float xv[8] = {fx0.x, fx0.y, fx0.z, fx0.w,
                                 fx1.x, fx1.y, fx1.z, fx1.w};
            const float wv[8] = {fw0.x, fw0.y, fw0.z, fw0.w,
                                 fw1.x, fw1.y, fw1.z, fw1.w};
            #pragma unroll
            for (int t = 0; t < 8; ++t)
                #pragma unroll
                for (int o = 0; o < 8; ++o)
                    acc[t][o] = fmaf(xv[t], wv[o], acc[t][o]);
        }
    }

    float* zbase = zp + (size_t)split * TT_TOTAL * E2;
    #pragma unroll
    for (int t = 0; t < 8; ++t) {
        const int tok = 4 * tg2 + (t & 3) + 64 * (t >> 2);
        float* row = zbase + (size_t)(tok0 + tok) * E2;
        float4 v0 = {acc[t][0], acc[t][1], acc[t][2], acc[t][3]};
        float4 v1 = {acc[t][4], acc[t][5], acc[t][6], acc[t][7]};
        *reinterpret_cast<float4*>(&row[4 * og2])      = v0;
        *reinterpret_cast<float4*>(&row[64 + 4 * og2]) = v1;
    }
}

// =====================================================================
// f32 topk + flagging: reduce splits (ascending), noise+bias, 9-rank
// selection; flag token if any adjacent gap among ranks 1..9 < DELTA.
// =====================================================================
template<int KS>
__launch_bounds__(256, 4)
__global__ void topkf_kernel(const float* __restrict__ zp,
                             const float* __restrict__ bias,
                             const float* __restrict__ noise_u,
                             float* __restrict__ out_probs,
                             float* __restrict__ out_idx,
                             int* __restrict__ flag_list,
                             int* __restrict__ flag_cnt)
{
    const int tid  = threadIdx.x;
    const int wid  = tid >> 6;
    const int lane = tid & 63;
    const int tok0 = blockIdx.x * 32;

    for (int tt = 0; tt < 8; ++tt) {
        const int tok = tok0 + wid * 8 + tt;
        const size_t gtok = (size_t)tok;

        float logit = 0.0f, noisy = 0.0f;
        #pragma unroll
        for (int s = 0; s < KS; ++s) {
            const float* row = zp + (size_t)s * TT_TOTAL * E2 + (size_t)tok * E2;
            logit += row[lane];
            noisy += row[EE + lane];
        }
        const float zv = noise_u[gtok * EE + lane] * softplus32(noisy)
                         + logit + bias[lane];

        float zw = zv;
        bool  sel = false;
        float vr[9];
        #pragma unroll
        for (int it = 0; it < 9; ++it) {
            float v  = zw;
            int   ix = lane;
            #pragma unroll
            for (int off = 32; off > 0; off >>= 1) {
                const float ov = __shfl_xor(v, off, 64);
                const int   oi = __shfl_xor(ix, off, 64);
                if (ov > v || (ov == v && oi < ix)) { v = ov; ix = oi; }
            }
            vr[it] = v;
            if (it < 8) {
                if (lane == ix) { sel = true; zw = -INFINITY; }
                if (lane == 0) out_idx[gtok * KK + it] = (float)ix;
            }
        }

        const float ex = sel ? expf(zv - vr[0]) : 0.0f;
        float den = ex;
        #pragma unroll
        for (int off = 32; off > 0; off >>= 1) den += __shfl_xor(den, off, 64);
        out_probs[gtok * EE + lane] = ex / den;

        // flagging: min adjacent gap over ranks 1..9
        if (lane == 0) {
            float mg = vr[0] - vr[1];
            #pragma unroll
            for (int i = 1; i < 8; ++i) mg = fminf(mg, vr[i] - vr[i + 1]);
            if (mg < DELTA) {
                const int p = atomicAdd(flag_cnt, 1);
                flag_list[p] = tok;
            }
        }
    }
}

// =====================================================================
// Repair: recompute flagged tokens' z-rows in f64, redo topk+softmax.
// =====================================================================
__launch_bounds__(256, 4)
__global__ void repair_kernel(const float* __restrict__ x,
                              const float* __restrict__ Wr,
                              const float* __restrict__ Wn,
                              const float* __restrict__ bias,
                              const float* __restrict__ noise_u,
                              float* __restrict__ out_probs,
                              float* __restrict__ out_idx,
                              const int* __restrict__ flag_list,
                              const int* __restrict__ flag_cnt)
{
    __shared__ double pp[2][E2];

    const int tid = threadIdx.x;
    const int o   = tid & 127;
    const int h   = tid >> 7;
    const int n   = flag_cnt[0];

    const float* wsrc = (o < EE) ? Wr + (size_t)o * DD
                                 : Wn + (size_t)(o - EE) * DD;

    for (int i = blockIdx.x; i < n; i += gridDim.x) {
        const int tok = flag_list[i];
        const float* xrow = x + (size_t)tok * DD;

        double p = 0.0;
        const int kb = h * (DD / 2);
        for (int k = 0; k < DD / 2; k += 4) {
            const float4 xv = *reinterpret_cast<const float4*>(&xrow[kb + k]);
            const float4 wv = *reinterpret_cast<const float4*>(&wsrc[kb + k]);
            p = fma((double)xv.x, (double)wv.x, p);
            p = fma((double)xv.y, (double)wv.y, p);
            p = fma((double)xv.z, (double)wv.z, p);
            p = fma((double)xv.w, (double)wv.w, p);
        }
        pp[h][o] = p;
        __syncthreads();

        if (tid < 64) {
            const int lane = tid;
            const double logit = pp[0][lane] + pp[1][lane];
            const double noisy = pp[0][EE + lane] + pp[1][EE + lane];
            const double zv = (double)noise_u[(size_t)tok * EE + lane]
                                  * softplus64(noisy)
                              + logit + (double)bias[lane];
            double zw = zv;
            bool   sel = false;
            double m0  = 0.0;
            #pragma unroll
            for (int it = 0; it < KK; ++it) {
                double v  = zw;
                int    ix = lane;
                #pragma unroll
                for (int off = 32; off > 0; off >>= 1) {
                    const double ov = __shfl_xor(v, off, 64);
                    const int    oi = __shfl_xor(ix, off, 64);
                    if (ov > v || (ov == v && oi < ix)) { v = ov; ix = oi; }
                }
                if (it == 0) m0 = v;
                if (lane == ix) { sel = true; zw = -INFINITY; }
                if (lane == 0) out_idx[(size_t)tok * KK + it] = (float)ix;
            }
            const double ex = sel ? exp(zv - m0) : 0.0;
            double den = ex;
            #pragma unroll
            for (int off = 32; off > 0; off >>= 1) den += __shfl_xor(den, off, 64);
            out_probs[(size_t)tok * EE + lane] = (float)(ex / den);
        }
        __syncthreads();
    }
}

__global__ void zero_kernel(int* __restrict__ cnt)
{
    if (threadIdx.x == 0) cnt[0] = 0;
}

__global__ void bias_kernel(const float* __restrict__ bias,
                            float* __restrict__ out_bias)
{
    const int e = threadIdx.x;
    if (e < EE) {
        // avg_load - total selections = 2048 - 131072 < 0 -> sign = -1 always
        out_bias[e] = bias[e] - 0.001f;
    }
}

// =====================================================================
// Tier-C fallback: verified R4 monolithic f64 kernel (small ws)
// =====================================================================
#define F_XT 34
#define F_WR 130
#define F_ZR 130
#define F_SMEM ((DK*F_XT + DK*F_WR)*8)

__launch_bounds__(256, 3)
__global__ void router_kernel(const float* __restrict__ x,
                              const float* __restrict__ Wr,
                              const float* __restrict__ Wn,
                              const float* __restrict__ bias,
                              const float* __restrict__ noise_u,
                              float* __restrict__ out_probs,
                              float* __restrict__ out_idx)
{
    __shared__ __align__(16) char smem_raw[F_SMEM];
    double (*xs)[F_XT] = reinterpret_cast<double(*)[F_XT]>(smem_raw);
    double (*wt)[F_WR] = reinterpret_cast<double(*)[F_WR]>(smem_raw + DK*F_XT*8);
    double (*zbuf)[F_ZR] = reinterpret_cast<double(*)[F_ZR]>(smem_raw);

    const int tid  = threadIdx.x;
    const int tok0 = blockIdx.x * 32;
    const int stok = tid >> 3;
    const int sfi  = tid & 7;
    const float* xsrc = x + (size_t)(tok0 + stok) * DD + sfi * 4;
    const float* wsrc[4];
    #pragma unroll
    for (int it = 0; it < 4; ++it) {
        const int r = it * 32 + stok;
        wsrc[it] = ((r < EE) ? (Wr + (size_t)r * DD)
                             : (Wn + (size_t)(r - EE) * DD)) + sfi * 4;
    }
    const int tg = tid >> 5;
    const int eg = tid & 31;

    double acc[4][4];
    #pragma unroll
    for (int t = 0; t < 4; ++t)
        #pragma unroll
        for (int i = 0; i < 4; ++i) acc[t][i] = 0.0;

    float4 xr  = *reinterpret_cast<const float4*>(xsrc);
    float4 wr0 = *reinterpret_cast<const float4*>(wsrc[0]);
    float4 wr1 = *reinterpret_cast<const float4*>(wsrc[1]);
    float4 wr2 = *reinterpret_cast<const float4*>(wsrc[2]);
    float4 wr3 = *reinterpret_cast<const float4*>(wsrc[3]);

    for (int c = 0; c < NC; ++c) {
        __syncthreads();
        {
            const int k0 = sfi * 4;
            xs[k0+0][stok] = (double)xr.x;  xs[k0+1][stok] = (double)xr.y;
            xs[k0+2][stok] = (double)xr.z;  xs[k0+3][stok] = (double)xr.w;
            wt[k0+0][stok      ] = (double)wr0.x; wt[k0+1][stok      ] = (double)wr0.y;
            wt[k0+2][stok      ] = (double)wr0.z; wt[k0+3][stok      ] = (double)wr0.w;
            wt[k0+0][stok + 32 ] = (double)wr1.x; wt[k0+1][stok + 32 ] = (double)wr1.y;
            wt[k0+2][stok + 32 ] = (double)wr1.z; wt[k0+3][stok + 32 ] = (double)wr1.w;
            wt[k0+0][stok + 64 ] = (double)wr2.x; wt[k0+1][stok + 64 ] = (double)wr2.y;
            wt[k0+2][stok + 64 ] = (double)wr2.z; wt[k0+3][stok + 64 ] = (double)wr2.w;
            wt[k0+0][stok + 96 ] = (double)wr3.x; wt[k0+1][stok + 96 ] = (double)wr3.y;
            wt[k0+2][stok + 96 ] = (double)wr3.z; wt[k0+3][stok + 96 ] = (double)wr3.w;
        }
        __syncthreads();
        if (c + 1 < NC) {
            const int off = (c + 1) * DK;
            xr  = *reinterpret_cast<const float4*>(xsrc + off);
            wr0 = *reinterpret_cast<const float4*>(wsrc[0] + off);
            wr1 = *reinterpret_cast<const float4*>(wsrc[1] + off);
            wr2 = *reinterpret_cast<const float4*>(wsrc[2] + off);
            wr3 = *reinterpret_cast<const float4*>(wsrc[3] + off);
        }
        #pragma unroll 4
        for (int k = 0; k < DK; ++k) {
            const double2_t xv0 = *reinterpret_cast<const double2_t*>(&xs[k][tg * 4]);
            const double2_t xv1 = *reinterpret_cast<const double2_t*>(&xs[k][tg * 4 + 2]);
            const double2_t w0  = *reinterpret_cast<const double2_t*>(&wt[k][2 * eg]);
            const double2_t w1  = *reinterpret_cast<const double2_t*>(&wt[k][64 + 2 * eg]);
            const double xvv[4] = {xv0.x, xv0.y, xv1.x, xv1.y};
            #pragma unroll
            for (int t = 0; t < 4; ++t) {
                acc[t][0] = fma(xvv[t], w0.x, acc[t][0]);
                acc[t][1] = fma(xvv[t], w0.y, acc[t][1]);
                acc[t][2] = fma(xvv[t], w1.x, acc[t][2]);
                acc[t][3] = fma(xvv[t], w1.y, acc[t][3]);
            }
        }
    }
    __syncthreads();
    #pragma unroll
    for (int t = 0; t < 4; ++t) {
        double2_t lo = {acc[t][0], acc[t][1]};
        double2_t hi = {acc[t][2], acc[t][3]};
        *reinterpret_cast<double2_t*>(&zbuf[tg * 4 + t][2 * eg])      = lo;
        *reinterpret_cast<double2_t*>(&zbuf[tg * 4 + t][64 + 2 * eg]) = hi;
    }
    __syncthreads();

    const int wid  = tid >> 6;
    const int lane = tid & 63;
    for (int tt = 0; tt < 8; ++tt) {
        const int tok = wid * 8 + tt;
        const size_t gtok = (size_t)tok0 + tok;
        const double logit = zbuf[tok][lane];
        const double noisy = zbuf[tok][EE + lane];
        const double zv = (double)noise_u[gtok * EE + lane] * softplus64(noisy)
                          + logit + (double)bias[lane];
        double zw = zv;
        bool   sel = false;
        double m0  = 0.0;
        #pragma unroll
        for (int it = 0; it < KK; ++it) {
            double v  = zw;
            int    ix = lane;
            #pragma unroll
            for (int off = 32; off > 0; off >>= 1) {
                const double ov = __shfl_xor(v, off, 64);
                const int    oi = __shfl_xor(ix, off, 64);
                if (ov > v || (ov == v && oi < ix)) { v = ov; ix = oi; }
            }
            if (it == 0) m0 = v;
            if (lane == ix) { sel = true; zw = -INFINITY; }
            if (lane == 0) out_idx[gtok * KK + it] = (float)ix;
        }
        const double ex = sel ? exp(zv - m0) : 0.0;
        double den = ex;
        #pragma unroll
        for (int off = 32; off > 0; off >>= 1) den += __shfl_xor(den, off, 64);
        out_probs[gtok * EE + lane] = (float)(ex / den);
    }
}

extern "C" void kernel_launch(void* const* d_in, const int* in_sizes, int n_in,
                              void* d_out, int out_size, void* d_ws, size_t ws_size,
                              hipStream_t stream)
{
    const float* x       = (const float*)d_in[0];
    const float* Wr      = (const float*)d_in[1];
    const float* Wn      = (const float*)d_in[2];
    const float* bias    = (const float*)d_in[3];
    const float* noise_u = (const float*)d_in[4];

    float* out       = (float*)d_out;
    float* out_probs = out;
    float* out_idx   = out + (size_t)TT_TOTAL * EE;
    float* out_bias  = out + (size_t)TT_TOTAL * EE + (size_t)TT_TOTAL * KK;

    const size_t zsplit = (size_t)TT_TOTAL * E2 * sizeof(float);  // 8 MiB
    const size_t extras = (size_t)(TT_TOTAL + 64) * sizeof(int);  // list + cnt

    int KS = 0;
    if      (ws_size >= 8 * zsplit + extras) KS = 8;
    else if (ws_size >= 4 * zsplit + extras) KS = 4;
    else if (ws_size >= 2 * zsplit + extras) KS = 2;

    if (KS > 0) {
        float* zp       = (float*)d_ws;
        int*   flag_list = (int*)((char*)d_ws + (size_t)KS * zsplit);
        int*   flag_cnt  = flag_list + TT_TOTAL;

        zero_kernel<<<1, 64, 0, stream>>>(flag_cnt);
        if (KS == 8) {
            gemmf32_kernel<8><<<128 * 8, 256, 0, stream>>>(x, Wr, Wn, zp);
            topkf_kernel<8><<<TT_TOTAL / 32, 256, 0, stream>>>(
                zp, bias, noise_u, out_probs, out_idx, flag_list, flag_cnt);
        } else if (KS == 4) {
            gemmf32_kernel<4><<<128 * 4, 256, 0, stream>>>(x, Wr, Wn, zp);
            topkf_kernel<4><<<TT_TOTAL / 32, 256, 0, stream>>>(
                zp, bias, noise_u, out_probs, out_idx, flag_list, flag_cnt);
        } else {
            gemmf32_kernel<2><<<128 * 2, 256, 0, stream>>>(x, Wr, Wn, zp);
            topkf_kernel<2><<<TT_TOTAL / 32, 256, 0, stream>>>(
                zp, bias, noise_u, out_probs, out_idx, flag_list, flag_cnt);
        }
        repair_kernel<<<128, 256, 0, stream>>>(x, Wr, Wn, bias, noise_u,
                                               out_probs, out_idx,
                                               flag_list, flag_cnt);
    } else {
        router_kernel<<<TT_TOTAL / 32, 256, 0, stream>>>(
            x, Wr, Wn, bias, noise_u, out_probs, out_idx);
    }
    bias_kernel<<<1, 64, 0, stream>>>(bias, out_bias);
}

// Round 12
// 391.392 us; speedup vs baseline: 1.3716x; 1.3716x over previous
//
#include <hip/hip_runtime.h>
#include <math.h>

#define BB 4
#define SS 4096
#define DD 2048
#define EE 64
#define KK 8
#define TT_TOTAL (BB*SS)      // 16384 tokens
#define E2 128                // stacked outputs (Wr 0..63, Wn 64..127)
#define DK 32
#define NC (DD/DK)
#define DELTA 1e-4f           // flag threshold (validated R11)

typedef double double2_t __attribute__((ext_vector_type(2)));

__device__ __forceinline__ double softplus64(double x) {
    return fmax(x, 0.0) + log1p(exp(-fabs(x)));
}
__device__ __forceinline__ float softplus32(float x) {
    return fmaxf(x, 0.0f) + log1pf(expf(-fabsf(x)));
}

// =====================================================================
// f32 GEMM: block 128 tok x 128 out, thread tile 8x8, f32 LDS+FMA.
// (validated R11) grid = 128*KS, 4 blocks/CU at KS=8.
// =====================================================================
#define ROWF 132   // 128 cols + 4 pad floats (528 B rows, 16B-aligned)

template<int KS>
__launch_bounds__(256, 4)
__global__ void gemmf32_kernel(const float* __restrict__ x,
                               const float* __restrict__ Wr,
                               const float* __restrict__ Wn,
                               float* __restrict__ zp)
{
    __shared__ __align__(16) float xs[DK][ROWF];   // 16896 B
    __shared__ __align__(16) float ws[DK][ROWF];   // 16896 B

    const int tid   = threadIdx.x;
    const int split = blockIdx.x % KS;
    const int bt    = blockIdx.x / KS;
    const int tok0  = bt * 128;
    const int kbase = split * (DD / KS);
    const int NCH   = (DD / KS) / DK;

    const int srow = tid & 127;
    const int skh  = tid >> 7;            // 0/1 -> k 0..15 / 16..31
    const float* xsrc = x + (size_t)(tok0 + srow) * DD + kbase + 16 * skh;
    const float* wsrc = ((srow < EE) ? Wr + (size_t)srow * DD
                                     : Wn + (size_t)(srow - EE) * DD)
                        + kbase + 16 * skh;

    const int og2 = tid & 15;
    const int tg2 = tid >> 4;

    float acc[8][8];
    #pragma unroll
    for (int t = 0; t < 8; ++t)
        #pragma unroll
        for (int o = 0; o < 8; ++o) acc[t][o] = 0.0f;

    float4 xa[4], wa[4];
    #pragma unroll
    for (int i = 0; i < 4; ++i) {
        xa[i] = *reinterpret_cast<const float4*>(xsrc + 4 * i);
        wa[i] = *reinterpret_cast<const float4*>(wsrc + 4 * i);
    }

    for (int c = 0; c < NCH; ++c) {
        __syncthreads();
        {
            const int k0 = 16 * skh;
            #pragma unroll
            for (int i = 0; i < 4; ++i) {
                xs[k0 + 4*i + 0][srow] = xa[i].x;
                xs[k0 + 4*i + 1][srow] = xa[i].y;
                xs[k0 + 4*i + 2][srow] = xa[i].z;
                xs[k0 + 4*i + 3][srow] = xa[i].w;
                ws[k0 + 4*i + 0][srow] = wa[i].x;
                ws[k0 + 4*i + 1][srow] = wa[i].y;
                ws[k0 + 4*i + 2][srow] = wa[i].z;
                ws[k0 + 4*i + 3][srow] = wa[i].w;
            }
        }
        __syncthreads();

        if (c + 1 < NCH) {
            const int off = (c + 1) * DK;
            #pragma unroll
            for (int i = 0; i < 4; ++i) {
                xa[i] = *reinterpret_cast<const float4*>(xsrc + off + 4 * i);
                wa[i] = *reinterpret_cast<const float4*>(wsrc + off + 4 * i);
            }
        }

        #pragma unroll 4
        for (int k = 0; k < DK; ++k) {
            const float4 fx0 = *reinterpret_cast<const float4*>(&xs[k][4 * tg2]);
            const float4 fx1 = *reinterpret_cast<const float4*>(&xs[k][64 + 4 * tg2]);
            const float4 fw0 = *reinterpret_cast<const float4*>(&ws[k][4 * og2]);
            const float4 fw1 = *reinterpret_cast<const float4*>(&ws[k][64 + 4 * og2]);
            const float xv[8] = {fx0.x, fx0.y, fx0.z, fx0.w,
                                 fx1.x, fx1.y, fx1.z, fx1.w};
            const float wv[8] = {fw0.x, fw0.y, fw0.z, fw0.w,
                                 fw1.x, fw1.y, fw1.z, fw1.w};
            #pragma unroll
            for (int t = 0; t < 8; ++t)
                #pragma unroll
                for (int o = 0; o < 8; ++o)
                    acc[t][o] = fmaf(xv[t], wv[o], acc[t][o]);
        }
    }

    float* zbase = zp + (size_t)split * TT_TOTAL * E2;
    #pragma unroll
    for (int t = 0; t < 8; ++t) {
        const int tok = 4 * tg2 + (t & 3) + 64 * (t >> 2);
        float* row = zbase + (size_t)(tok0 + tok) * E2;
        float4 v0 = {acc[t][0], acc[t][1], acc[t][2], acc[t][3]};
        float4 v1 = {acc[t][4], acc[t][5], acc[t][6], acc[t][7]};
        *reinterpret_cast<float4*>(&row[4 * og2])      = v0;
        *reinterpret_cast<float4*>(&row[64 + 4 * og2]) = v1;
    }
}

// =====================================================================
// f32 topk + gap-based flagging (validated R11)
// =====================================================================
template<int KS>
__launch_bounds__(256, 4)
__global__ void topkf_kernel(const float* __restrict__ zp,
                             const float* __restrict__ bias,
                             const float* __restrict__ noise_u,
                             float* __restrict__ out_probs,
                             float* __restrict__ out_idx,
                             int* __restrict__ flag_list,
                             int* __restrict__ flag_cnt)
{
    const int tid  = threadIdx.x;
    const int wid  = tid >> 6;
    const int lane = tid & 63;
    const int tok0 = blockIdx.x * 32;

    for (int tt = 0; tt < 8; ++tt) {
        const int tok = tok0 + wid * 8 + tt;
        const size_t gtok = (size_t)tok;

        float logit = 0.0f, noisy = 0.0f;
        #pragma unroll
        for (int s = 0; s < KS; ++s) {
            const float* row = zp + (size_t)s * TT_TOTAL * E2 + (size_t)tok * E2;
            logit += row[lane];
            noisy += row[EE + lane];
        }
        const float zv = noise_u[gtok * EE + lane] * softplus32(noisy)
                         + logit + bias[lane];

        float zw = zv;
        bool  sel = false;
        float vr[9];
        #pragma unroll
        for (int it = 0; it < 9; ++it) {
            float v  = zw;
            int   ix = lane;
            #pragma unroll
            for (int off = 32; off > 0; off >>= 1) {
                const float ov = __shfl_xor(v, off, 64);
                const int   oi = __shfl_xor(ix, off, 64);
                if (ov > v || (ov == v && oi < ix)) { v = ov; ix = oi; }
            }
            vr[it] = v;
            if (it < 8) {
                if (lane == ix) { sel = true; zw = -INFINITY; }
                if (lane == 0) out_idx[gtok * KK + it] = (float)ix;
            }
        }

        const float ex = sel ? expf(zv - vr[0]) : 0.0f;
        float den = ex;
        #pragma unroll
        for (int off = 32; off > 0; off >>= 1) den += __shfl_xor(den, off, 64);
        out_probs[gtok * EE + lane] = ex / den;

        if (lane == 0) {
            float mg = vr[0] - vr[1];
            #pragma unroll
            for (int i = 1; i < 8; ++i) mg = fminf(mg, vr[i] - vr[i + 1]);
            if (mg < DELTA) {
                const int p = atomicAdd(flag_cnt, 1);
                flag_list[p] = tok;
            }
        }
    }
}

// =====================================================================
// Repair v2: latency-optimized. 256 blocks (~n/256 tokens each).
// Per thread (o,h): 4 independent f64 chains, 8 loads batched/iter.
// =====================================================================
__launch_bounds__(256, 4)
__global__ void repair_kernel(const float* __restrict__ x,
                              const float* __restrict__ Wr,
                              const float* __restrict__ Wn,
                              const float* __restrict__ bias,
                              const float* __restrict__ noise_u,
                              float* __restrict__ out_probs,
                              float* __restrict__ out_idx,
                              const int* __restrict__ flag_list,
                              const int* __restrict__ flag_cnt)
{
    __shared__ double pp[2][E2];

    const int tid = threadIdx.x;
    const int o   = tid & 127;
    const int h   = tid >> 7;
    const int n   = flag_cnt[0];

    const float* wsrc = ((o < EE) ? Wr + (size_t)o * DD
                                  : Wn + (size_t)(o - EE) * DD) + h * (DD / 2);

    for (int i = blockIdx.x; i < n; i += gridDim.x) {
        const int tok = flag_list[i];
        const float* xrow = x + (size_t)tok * DD + h * (DD / 2);

        double p0 = 0.0, p1 = 0.0, p2 = 0.0, p3 = 0.0;
        #pragma unroll 2
        for (int k = 0; k < DD / 2; k += 16) {
            const float4 xv0 = *reinterpret_cast<const float4*>(&xrow[k]);
            const float4 xv1 = *reinterpret_cast<const float4*>(&xrow[k + 4]);
            const float4 xv2 = *reinterpret_cast<const float4*>(&xrow[k + 8]);
            const float4 xv3 = *reinterpret_cast<const float4*>(&xrow[k + 12]);
            const float4 wv0 = *reinterpret_cast<const float4*>(&wsrc[k]);
            const float4 wv1 = *reinterpret_cast<const float4*>(&wsrc[k + 4]);
            const float4 wv2 = *reinterpret_cast<const float4*>(&wsrc[k + 8]);
            const float4 wv3 = *reinterpret_cast<const float4*>(&wsrc[k + 12]);
            p0 = fma((double)xv0.x, (double)wv0.x, p0);
            p0 = fma((double)xv0.y, (double)wv0.y, p0);
            p0 = fma((double)xv0.z, (double)wv0.z, p0);
            p0 = fma((double)xv0.w, (double)wv0.w, p0);
            p1 = fma((double)xv1.x, (double)wv1.x, p1);
            p1 = fma((double)xv1.y, (double)wv1.y, p1);
            p1 = fma((double)xv1.z, (double)wv1.z, p1);
            p1 = fma((double)xv1.w, (double)wv1.w, p1);
            p2 = fma((double)xv2.x, (double)wv2.x, p2);
            p2 = fma((double)xv2.y, (double)wv2.y, p2);
            p2 = fma((double)xv2.z, (double)wv2.z, p2);
            p2 = fma((double)xv2.w, (double)wv2.w, p2);
            p3 = fma((double)xv3.x, (double)wv3.x, p3);
            p3 = fma((double)xv3.y, (double)wv3.y, p3);
            p3 = fma((double)xv3.z, (double)wv3.z, p3);
            p3 = fma((double)xv3.w, (double)wv3.w, p3);
        }
        pp[h][o] = (p0 + p1) + (p2 + p3);
        __syncthreads();

        if (tid < 64) {
            const int lane = tid;
            const double logit = pp[0][lane] + pp[1][lane];
            const double noisy = pp[0][EE + lane] + pp[1][EE + lane];
            const double zv = (double)noise_u[(size_t)tok * EE + lane]
                                  * softplus64(noisy)
                              + logit + (double)bias[lane];
            double zw = zv;
            bool   sel = false;
            double m0  = 0.0;
            #pragma unroll
            for (int it = 0; it < KK; ++it) {
                double v  = zw;
                int    ix = lane;
                #pragma unroll
                for (int off = 32; off > 0; off >>= 1) {
                    const double ov = __shfl_xor(v, off, 64);
                    const int    oi = __shfl_xor(ix, off, 64);
                    if (ov > v || (ov == v && oi < ix)) { v = ov; ix = oi; }
                }
                if (it == 0) m0 = v;
                if (lane == ix) { sel = true; zw = -INFINITY; }
                if (lane == 0) out_idx[(size_t)tok * KK + it] = (float)ix;
            }
            const double ex = sel ? exp(zv - m0) : 0.0;
            double den = ex;
            #pragma unroll
            for (int off = 32; off > 0; off >>= 1) den += __shfl_xor(den, off, 64);
            out_probs[(size_t)tok * EE + lane] = (float)(ex / den);
        }
        __syncthreads();
    }
}

__global__ void zero_kernel(int* __restrict__ cnt)
{
    if (threadIdx.x == 0) cnt[0] = 0;
}

__global__ void bias_kernel(const float* __restrict__ bias,
                            float* __restrict__ out_bias)
{
    const int e = threadIdx.x;
    if (e < EE) {
        // avg_load - total selections = 2048 - 131072 < 0 -> sign = -1 always
        out_bias[e] = bias[e] - 0.001f;
    }
}

// =====================================================================
// Tier-C fallback: verified R4 monolithic f64 kernel (small ws)
// =====================================================================
#define F_XT 34
#define F_WR 130
#define F_ZR 130
#define F_SMEM ((DK*F_XT + DK*F_WR)*8)

__launch_bounds__(256, 3)
__global__ void router_kernel(const float* __restrict__ x,
                              const float* __restrict__ Wr,
                              const float* __restrict__ Wn,
                              const float* __restrict__ bias,
                              const float* __restrict__ noise_u,
                              float* __restrict__ out_probs,
                              float* __restrict__ out_idx)
{
    __shared__ __align__(16) char smem_raw[F_SMEM];
    double (*xs)[F_XT] = reinterpret_cast<double(*)[F_XT]>(smem_raw);
    double (*wt)[F_WR] = reinterpret_cast<double(*)[F_WR]>(smem_raw + DK*F_XT*8);
    double (*zbuf)[F_ZR] = reinterpret_cast<double(*)[F_ZR]>(smem_raw);

    const int tid  = threadIdx.x;
    const int tok0 = blockIdx.x * 32;
    const int stok = tid >> 3;
    const int sfi  = tid & 7;
    const float* xsrc = x + (size_t)(tok0 + stok) * DD + sfi * 4;
    const float* wsrc[4];
    #pragma unroll
    for (int it = 0; it < 4; ++it) {
        const int r = it * 32 + stok;
        wsrc[it] = ((r < EE) ? (Wr + (size_t)r * DD)
                             : (Wn + (size_t)(r - EE) * DD)) + sfi * 4;
    }
    const int tg = tid >> 5;
    const int eg = tid & 31;

    double acc[4][4];
    #pragma unroll
    for (int t = 0; t < 4; ++t)
        #pragma unroll
        for (int i = 0; i < 4; ++i) acc[t][i] = 0.0;

    float4 xr  = *reinterpret_cast<const float4*>(xsrc);
    float4 wr0 = *reinterpret_cast<const float4*>(wsrc[0]);
    float4 wr1 = *reinterpret_cast<const float4*>(wsrc[1]);
    float4 wr2 = *reinterpret_cast<const float4*>(wsrc[2]);
    float4 wr3 = *reinterpret_cast<const float4*>(wsrc[3]);

    for (int c = 0; c < NC; ++c) {
        __syncthreads();
        {
            const int k0 = sfi * 4;
            xs[k0+0][stok] = (double)xr.x;  xs[k0+1][stok] = (double)xr.y;
            xs[k0+2][stok] = (double)xr.z;  xs[k0+3][stok] = (double)xr.w;
            wt[k0+0][stok      ] = (double)wr0.x; wt[k0+1][stok      ] = (double)wr0.y;
            wt[k0+2][stok      ] = (double)wr0.z; wt[k0+3][stok      ] = (double)wr0.w;
            wt[k0+0][stok + 32 ] = (double)wr1.x; wt[k0+1][stok + 32 ] = (double)wr1.y;
            wt[k0+2][stok + 32 ] = (double)wr1.z; wt[k0+3][stok + 32 ] = (double)wr1.w;
            wt[k0+0][stok + 64 ] = (double)wr2.x; wt[k0+1][stok + 64 ] = (double)wr2.y;
            wt[k0+2][stok + 64 ] = (double)wr2.z; wt[k0+3][stok + 64 ] = (double)wr2.w;
            wt[k0+0][stok + 96 ] = (double)wr3.x; wt[k0+1][stok + 96 ] = (double)wr3.y;
            wt[k0+2][stok + 96 ] = (double)wr3.z; wt[k0+3][stok + 96 ] = (double)wr3.w;
        }
        __syncthreads();
        if (c + 1 < NC) {
            const int off = (c + 1) * DK;
            xr  = *reinterpret_cast<const float4*>(xsrc + off);
            wr0 = *reinterpret_cast<const float4*>(wsrc[0] + off);
            wr1 = *reinterpret_cast<const float4*>(wsrc[1] + off);
            wr2 = *reinterpret_cast<const float4*>(wsrc[2] + off);
            wr3 = *reinterpret_cast<const float4*>(wsrc[3] + off);
        }
        #pragma unroll 4
        for (int k = 0; k < DK; ++k) {
            const double2_t xv0 = *reinterpret_cast<const double2_t*>(&xs[k][tg * 4]);
            const double2_t xv1 = *reinterpret_cast<const double2_t*>(&xs[k][tg * 4 + 2]);
            const double2_t w0  = *reinterpret_cast<const double2_t*>(&wt[k][2 * eg]);
            const double2_t w1  = *reinterpret_cast<const double2_t*>(&wt[k][64 + 2 * eg]);
            const double xvv[4] = {xv0.x, xv0.y, xv1.x, xv1.y};
            #pragma unroll
            for (int t = 0; t < 4; ++t) {
                acc[t][0] = fma(xvv[t], w0.x, acc[t][0]);
                acc[t][1] = fma(xvv[t], w0.y, acc[t][1]);
                acc[t][2] = fma(xvv[t], w1.x, acc[t][2]);
                acc[t][3] = fma(xvv[t], w1.y, acc[t][3]);
            }
        }
    }
    __syncthreads();
    #pragma unroll
    for (int t = 0; t < 4; ++t) {
        double2_t lo = {acc[t][0], acc[t][1]};
        double2_t hi = {acc[t][2], acc[t][3]};
        *reinterpret_cast<double2_t*>(&zbuf[tg * 4 + t][2 * eg])      = lo;
        *reinterpret_cast<double2_t*>(&zbuf[tg * 4 + t][64 + 2 * eg]) = hi;
    }
    __syncthreads();

    const int wid  = tid >> 6;
    const int lane = tid & 63;
    for (int tt = 0; tt < 8; ++tt) {
        const int tok = wid * 8 + tt;
        const size_t gtok = (size_t)tok0 + tok;
        const double logit = zbuf[tok][lane];
        const double noisy = zbuf[tok][EE + lane];
        const double zv = (double)noise_u[gtok * EE + lane] * softplus64(noisy)
                          + logit + (double)bias[lane];
        double zw = zv;
        bool   sel = false;
        double m0  = 0.0;
        #pragma unroll
        for (int it = 0; it < KK; ++it) {
            double v  = zw;
            int    ix = lane;
            #pragma unroll
            for (int off = 32; off > 0; off >>= 1) {
                const double ov = __shfl_xor(v, off, 64);
                const int    oi = __shfl_xor(ix, off, 64);
                if (ov > v || (ov == v && oi < ix)) { v = ov; ix = oi; }
            }
            if (it == 0) m0 = v;
            if (lane == ix) { sel = true; zw = -INFINITY; }
            if (lane == 0) out_idx[gtok * KK + it] = (float)ix;
        }
        const double ex = sel ? exp(zv - m0) : 0.0;
        double den = ex;
        #pragma unroll
        for (int off = 32; off > 0; off >>= 1) den += __shfl_xor(den, off, 64);
        out_probs[gtok * EE + lane] = (float)(ex / den);
    }
}

extern "C" void kernel_launch(void* const* d_in, const int* in_sizes, int n_in,
                              void* d_out, int out_size, void* d_ws, size_t ws_size,
                              hipStream_t stream)
{
    const float* x       = (const float*)d_in[0];
    const float* Wr      = (const float*)d_in[1];
    const float* Wn      = (const float*)d_in[2];
    const float* bias    = (const float*)d_in[3];
    const float* noise_u = (const float*)d_in[4];

    float* out       = (float*)d_out;
    float* out_probs = out;
    float* out_idx   = out + (size_t)TT_TOTAL * EE;
    float* out_bias  = out + (size_t)TT_TOTAL * EE + (size_t)TT_TOTAL * KK;

    const size_t zsplit = (size_t)TT_TOTAL * E2 * sizeof(float);  // 8 MiB
    const size_t extras = (size_t)(TT_TOTAL + 64) * sizeof(int);  // list + cnt

    int KS = 0;
    if      (ws_size >= 8 * zsplit + extras) KS = 8;
    else if (ws_size >= 4 * zsplit + extras) KS = 4;
    else if (ws_size >= 2 * zsplit + extras) KS = 2;

    if (KS > 0) {
        float* zp        = (float*)d_ws;
        int*   flag_list = (int*)((char*)d_ws + (size_t)KS * zsplit);
        int*   flag_cnt  = flag_list + TT_TOTAL;

        zero_kernel<<<1, 64, 0, stream>>>(flag_cnt);
        if (KS == 8) {
            gemmf32_kernel<8><<<128 * 8, 256, 0, stream>>>(x, Wr, Wn, zp);
            topkf_kernel<8><<<TT_TOTAL / 32, 256, 0, stream>>>(
                zp, bias, noise_u, out_probs, out_idx, flag_list, flag_cnt);
        } else if (KS == 4) {
            gemmf32_kernel<4><<<128 * 4, 256, 0, stream>>>(x, Wr, Wn, zp);
            topkf_kernel<4><<<TT_TOTAL / 32, 256, 0, stream>>>(
                zp, bias, noise_u, out_probs, out_idx, flag_list, flag_cnt);
        } else {
            gemmf32_kernel<2><<<128 * 2, 256, 0, stream>>>(x, Wr, Wn, zp);
            topkf_kernel<2><<<TT_TOTAL / 32, 256, 0, stream>>>(
                zp, bias, noise_u, out_probs, out_idx, flag_list, flag_cnt);
        }
        repair_kernel<<<256, 256, 0, stream>>>(x, Wr, Wn, bias, noise_u,
                                               out_probs, out_idx,
                                               flag_list, flag_cnt);
    } else {
        router_kernel<<<TT_TOTAL / 32, 256, 0, stream>>>(
            x, Wr, Wn, bias, noise_u, out_probs, out_idx);
    }
    bias_kernel<<<1, 64, 0, stream>>>(bias, out_bias);
}

// Round 13
// 314.944 us; speedup vs baseline: 1.7045x; 1.2427x over previous
//
#include <hip/hip_runtime.h>
#include <math.h>

#define BB 4
#define SS 4096
#define DD 2048
#define EE 64
#define KK 8
#define TT_TOTAL (BB*SS)      // 16384 tokens
#define E2 128                // stacked outputs (Wr 0..63, Wn 64..127)
#define DK 32
#define NC (DD/DK)
#define DELTA 1e-4f           // flag threshold (validated R11/R12)

typedef double double2_t __attribute__((ext_vector_type(2)));

__device__ __forceinline__ double softplus64(double x) {
    return fmax(x, 0.0) + log1p(exp(-fabs(x)));
}
__device__ __forceinline__ float softplus32(float x) {
    return fmaxf(x, 0.0f) + log1pf(expf(-fabsf(x)));
}

// =====================================================================
// f32 GEMM: block 128 tok x 128 out, thread tile 8x8, f32 LDS+FMA.
// (validated R11/R12) grid = 128*KS, 4 blocks/CU at KS=8.
// =====================================================================
#define ROWF 132   // 128 cols + 4 pad floats (528 B rows, 16B-aligned)

template<int KS>
__launch_bounds__(256, 4)
__global__ void gemmf32_kernel(const float* __restrict__ x,
                               const float* __restrict__ Wr,
                               const float* __restrict__ Wn,
                               float* __restrict__ zp)
{
    __shared__ __align__(16) float xs[DK][ROWF];   // 16896 B
    __shared__ __align__(16) float ws[DK][ROWF];   // 16896 B

    const int tid   = threadIdx.x;
    const int split = blockIdx.x % KS;
    const int bt    = blockIdx.x / KS;
    const int tok0  = bt * 128;
    const int kbase = split * (DD / KS);
    const int NCH   = (DD / KS) / DK;

    const int srow = tid & 127;
    const int skh  = tid >> 7;            // 0/1 -> k 0..15 / 16..31
    const float* xsrc = x + (size_t)(tok0 + srow) * DD + kbase + 16 * skh;
    const float* wsrc = ((srow < EE) ? Wr + (size_t)srow * DD
                                     : Wn + (size_t)(srow - EE) * DD)
                        + kbase + 16 * skh;

    const int og2 = tid & 15;
    const int tg2 = tid >> 4;

    float acc[8][8];
    #pragma unroll
    for (int t = 0; t < 8; ++t)
        #pragma unroll
        for (int o = 0; o < 8; ++o) acc[t][o] = 0.0f;

    float4 xa[4], wa[4];
    #pragma unroll
    for (int i = 0; i < 4; ++i) {
        xa[i] = *reinterpret_cast<const float4*>(xsrc + 4 * i);
        wa[i] = *reinterpret_cast<const float4*>(wsrc + 4 * i);
    }

    for (int c = 0; c < NCH; ++c) {
        __syncthreads();
        {
            const int k0 = 16 * skh;
            #pragma unroll
            for (int i = 0; i < 4; ++i) {
                xs[k0 + 4*i + 0][srow] = xa[i].x;
                xs[k0 + 4*i + 1][srow] = xa[i].y;
                xs[k0 + 4*i + 2][srow] = xa[i].z;
                xs[k0 + 4*i + 3][srow] = xa[i].w;
                ws[k0 + 4*i + 0][srow] = wa[i].x;
                ws[k0 + 4*i + 1][srow] = wa[i].y;
                ws[k0 + 4*i + 2][srow] = wa[i].z;
                ws[k0 + 4*i + 3][srow] = wa[i].w;
            }
        }
        __syncthreads();

        if (c + 1 < NCH) {
            const int off = (c + 1) * DK;
            #pragma unroll
            for (int i = 0; i < 4; ++i) {
                xa[i] = *reinterpret_cast<const float4*>(xsrc + off + 4 * i);
                wa[i] = *reinterpret_cast<const float4*>(wsrc + off + 4 * i);
            }
        }

        #pragma unroll 4
        for (int k = 0; k < DK; ++k) {
            const float4 fx0 = *reinterpret_cast<const float4*>(&xs[k][4 * tg2]);
            const float4 fx1 = *reinterpret_cast<const float4*>(&xs[k][64 + 4 * tg2]);
            const float4 fw0 = *reinterpret_cast<const float4*>(&ws[k][4 * og2]);
            const float4 fw1 = *reinterpret_cast<const float4*>(&ws[k][64 + 4 * og2]);
            const float xv[8] = {fx0.x, fx0.y, fx0.z, fx0.w,
                                 fx1.x, fx1.y, fx1.z, fx1.w};
            const float wv[8] = {fw0.x, fw0.y, fw0.z, fw0.w,
                                 fw1.x, fw1.y, fw1.z, fw1.w};
            #pragma unroll
            for (int t = 0; t < 8; ++t)
                #pragma unroll
                for (int o = 0; o < 8; ++o)
                    acc[t][o] = fmaf(xv[t], wv[o], acc[t][o]);
        }
    }

    float* zbase = zp + (size_t)split * TT_TOTAL * E2;
    #pragma unroll
    for (int t = 0; t < 8; ++t) {
        const int tok = 4 * tg2 + (t & 3) + 64 * (t >> 2);
        float* row = zbase + (size_t)(tok0 + tok) * E2;
        float4 v0 = {acc[t][0], acc[t][1], acc[t][2], acc[t][3]};
        float4 v1 = {acc[t][4], acc[t][5], acc[t][6], acc[t][7]};
        *reinterpret_cast<float4*>(&row[4 * og2])      = v0;
        *reinterpret_cast<float4*>(&row[64 + 4 * og2]) = v1;
    }
}

// =====================================================================
// f32 topk + gap-based flagging (validated R11/R12)
// =====================================================================
template<int KS>
__launch_bounds__(256, 4)
__global__ void topkf_kernel(const float* __restrict__ zp,
                             const float* __restrict__ bias,
                             const float* __restrict__ noise_u,
                             float* __restrict__ out_probs,
                             float* __restrict__ out_idx,
                             int* __restrict__ flag_list,
                             int* __restrict__ flag_cnt)
{
    const int tid  = threadIdx.x;
    const int wid  = tid >> 6;
    const int lane = tid & 63;
    const int tok0 = blockIdx.x * 32;

    for (int tt = 0; tt < 8; ++tt) {
        const int tok = tok0 + wid * 8 + tt;
        const size_t gtok = (size_t)tok;

        float logit = 0.0f, noisy = 0.0f;
        #pragma unroll
        for (int s = 0; s < KS; ++s) {
            const float* row = zp + (size_t)s * TT_TOTAL * E2 + (size_t)tok * E2;
            logit += row[lane];
            noisy += row[EE + lane];
        }
        const float zv = noise_u[gtok * EE + lane] * softplus32(noisy)
                         + logit + bias[lane];

        float zw = zv;
        bool  sel = false;
        float vr[9];
        #pragma unroll
        for (int it = 0; it < 9; ++it) {
            float v  = zw;
            int   ix = lane;
            #pragma unroll
            for (int off = 32; off > 0; off >>= 1) {
                const float ov = __shfl_xor(v, off, 64);
                const int   oi = __shfl_xor(ix, off, 64);
                if (ov > v || (ov == v && oi < ix)) { v = ov; ix = oi; }
            }
            vr[it] = v;
            if (it < 8) {
                if (lane == ix) { sel = true; zw = -INFINITY; }
                if (lane == 0) out_idx[gtok * KK + it] = (float)ix;
            }
        }

        const float ex = sel ? expf(zv - vr[0]) : 0.0f;
        float den = ex;
        #pragma unroll
        for (int off = 32; off > 0; off >>= 1) den += __shfl_xor(den, off, 64);
        out_probs[gtok * EE + lane] = ex / den;

        if (lane == 0) {
            float mg = vr[0] - vr[1];
            #pragma unroll
            for (int i = 1; i < 8; ++i) mg = fminf(mg, vr[i] - vr[i + 1]);
            if (mg < DELTA) {
                const int p = atomicAdd(flag_cnt, 1);
                flag_list[p] = tok;
            }
        }
    }
}

// =====================================================================
// Repair v3: coalesced. Per token: x row staged to LDS; each wave does
// 32 outputs, k split across lanes (lane l reads W[o][4l+256j] -> fully
// coalesced), 2 outputs in flight, f64 chains + shfl_xor tree reduce.
// =====================================================================
__launch_bounds__(256, 4)
__global__ void repair_kernel(const float* __restrict__ x,
                              const float* __restrict__ Wr,
                              const float* __restrict__ Wn,
                              const float* __restrict__ bias,
                              const float* __restrict__ noise_u,
                              float* __restrict__ out_probs,
                              float* __restrict__ out_idx,
                              const int* __restrict__ flag_list,
                              const int* __restrict__ flag_cnt)
{
    __shared__ __align__(16) float xsh[DD];   // 8 KB
    __shared__ double zz[E2];                 // 1 KB

    const int tid  = threadIdx.x;
    const int wv   = tid >> 6;
    const int lane = tid & 63;
    const int n    = flag_cnt[0];

    for (int i = blockIdx.x; i < n; i += gridDim.x) {
        const int tok = flag_list[i];

        // stage x row coalesced: 512 float4 over 256 threads
        {
            const float4* src = reinterpret_cast<const float4*>(x + (size_t)tok * DD);
            float4* dst = reinterpret_cast<float4*>(xsh);
            dst[tid]       = src[tid];
            dst[tid + 256] = src[tid + 256];
        }
        __syncthreads();

        // each wave: 32 outputs, 2 at a time
        for (int j = 0; j < 32; j += 2) {
            const int o0 = wv * 32 + j;
            const int o1 = o0 + 1;
            const float* w0 = (o0 < EE) ? Wr + (size_t)o0 * DD
                                        : Wn + (size_t)(o0 - EE) * DD;
            const float* w1 = (o1 < EE) ? Wr + (size_t)o1 * DD
                                        : Wn + (size_t)(o1 - EE) * DD;
            double p0a = 0.0, p0b = 0.0, p1a = 0.0, p1b = 0.0;
            #pragma unroll
            for (int jj = 0; jj < 8; jj += 2) {
                const int ka = jj * 256 + lane * 4;
                const int kb = (jj + 1) * 256 + lane * 4;
                const float4 xa = *reinterpret_cast<const float4*>(&xsh[ka]);
                const float4 xb = *reinterpret_cast<const float4*>(&xsh[kb]);
                const float4 wa0 = *reinterpret_cast<const float4*>(&w0[ka]);
                const float4 wb0 = *reinterpret_cast<const float4*>(&w0[kb]);
                const float4 wa1 = *reinterpret_cast<const float4*>(&w1[ka]);
                const float4 wb1 = *reinterpret_cast<const float4*>(&w1[kb]);
                p0a = fma((double)xa.x, (double)wa0.x, p0a);
                p0a = fma((double)xa.y, (double)wa0.y, p0a);
                p0a = fma((double)xa.z, (double)wa0.z, p0a);
                p0a = fma((double)xa.w, (double)wa0.w, p0a);
                p0b = fma((double)xb.x, (double)wb0.x, p0b);
                p0b = fma((double)xb.y, (double)wb0.y, p0b);
                p0b = fma((double)xb.z, (double)wb0.z, p0b);
                p0b = fma((double)xb.w, (double)wb0.w, p0b);
                p1a = fma((double)xa.x, (double)wa1.x, p1a);
                p1a = fma((double)xa.y, (double)wa1.y, p1a);
                p1a = fma((double)xa.z, (double)wa1.z, p1a);
                p1a = fma((double)xa.w, (double)wa1.w, p1a);
                p1b = fma((double)xb.x, (double)wb1.x, p1b);
                p1b = fma((double)xb.y, (double)wb1.y, p1b);
                p1b = fma((double)xb.z, (double)wb1.z, p1b);
                p1b = fma((double)xb.w, (double)wb1.w, p1b);
            }
            double p0 = p0a + p0b;
            double p1 = p1a + p1b;
            #pragma unroll
            for (int off = 32; off > 0; off >>= 1) {
                p0 += __shfl_xor(p0, off, 64);
                p1 += __shfl_xor(p1, off, 64);
            }
            if (lane == 0) { zz[o0] = p0; zz[o1] = p1; }
        }
        __syncthreads();

        if (tid < 64) {
            const int l = tid;
            const double logit = zz[l];
            const double noisy = zz[EE + l];
            const double zv = (double)noise_u[(size_t)tok * EE + l]
                                  * softplus64(noisy)
                              + logit + (double)bias[l];
            double zw = zv;
            bool   sel = false;
            double m0  = 0.0;
            #pragma unroll
            for (int it = 0; it < KK; ++it) {
                double v  = zw;
                int    ix = l;
                #pragma unroll
                for (int off = 32; off > 0; off >>= 1) {
                    const double ov = __shfl_xor(v, off, 64);
                    const int    oi = __shfl_xor(ix, off, 64);
                    if (ov > v || (ov == v && oi < ix)) { v = ov; ix = oi; }
                }
                if (it == 0) m0 = v;
                if (l == ix) { sel = true; zw = -INFINITY; }
                if (l == 0) out_idx[(size_t)tok * KK + it] = (float)ix;
            }
            const double ex = sel ? exp(zv - m0) : 0.0;
            double den = ex;
            #pragma unroll
            for (int off = 32; off > 0; off >>= 1) den += __shfl_xor(den, off, 64);
            out_probs[(size_t)tok * EE + l] = (float)(ex / den);
        }
        __syncthreads();
    }
}

__global__ void zero_kernel(int* __restrict__ cnt)
{
    if (threadIdx.x == 0) cnt[0] = 0;
}

__global__ void bias_kernel(const float* __restrict__ bias,
                            float* __restrict__ out_bias)
{
    const int e = threadIdx.x;
    if (e < EE) {
        // avg_load - total selections = 2048 - 131072 < 0 -> sign = -1 always
        out_bias[e] = bias[e] - 0.001f;
    }
}

// =====================================================================
// Tier-C fallback: verified R4 monolithic f64 kernel (small ws)
// =====================================================================
#define F_XT 34
#define F_WR 130
#define F_ZR 130
#define F_SMEM ((DK*F_XT + DK*F_WR)*8)

__launch_bounds__(256, 3)
__global__ void router_kernel(const float* __restrict__ x,
                              const float* __restrict__ Wr,
                              const float* __restrict__ Wn,
                              const float* __restrict__ bias,
                              const float* __restrict__ noise_u,
                              float* __restrict__ out_probs,
                              float* __restrict__ out_idx)
{
    __shared__ __align__(16) char smem_raw[F_SMEM];
    double (*xs)[F_XT] = reinterpret_cast<double(*)[F_XT]>(smem_raw);
    double (*wt)[F_WR] = reinterpret_cast<double(*)[F_WR]>(smem_raw + DK*F_XT*8);
    double (*zbuf)[F_ZR] = reinterpret_cast<double(*)[F_ZR]>(smem_raw);

    const int tid  = threadIdx.x;
    const int tok0 = blockIdx.x * 32;
    const int stok = tid >> 3;
    const int sfi  = tid & 7;
    const float* xsrc = x + (size_t)(tok0 + stok) * DD + sfi * 4;
    const float* wsrc[4];
    #pragma unroll
    for (int it = 0; it < 4; ++it) {
        const int r = it * 32 + stok;
        wsrc[it] = ((r < EE) ? (Wr + (size_t)r * DD)
                             : (Wn + (size_t)(r - EE) * DD)) + sfi * 4;
    }
    const int tg = tid >> 5;
    const int eg = tid & 31;

    double acc[4][4];
    #pragma unroll
    for (int t = 0; t < 4; ++t)
        #pragma unroll
        for (int i = 0; i < 4; ++i) acc[t][i] = 0.0;

    float4 xr  = *reinterpret_cast<const float4*>(xsrc);
    float4 wr0 = *reinterpret_cast<const float4*>(wsrc[0]);
    float4 wr1 = *reinterpret_cast<const float4*>(wsrc[1]);
    float4 wr2 = *reinterpret_cast<const float4*>(wsrc[2]);
    float4 wr3 = *reinterpret_cast<const float4*>(wsrc[3]);

    for (int c = 0; c < NC; ++c) {
        __syncthreads();
        {
            const int k0 = sfi * 4;
            xs[k0+0][stok] = (double)xr.x;  xs[k0+1][stok] = (double)xr.y;
            xs[k0+2][stok] = (double)xr.z;  xs[k0+3][stok] = (double)xr.w;
            wt[k0+0][stok      ] = (double)wr0.x; wt[k0+1][stok      ] = (double)wr0.y;
            wt[k0+2][stok      ] = (double)wr0.z; wt[k0+3][stok      ] = (double)wr0.w;
            wt[k0+0][stok + 32 ] = (double)wr1.x; wt[k0+1][stok + 32 ] = (double)wr1.y;
            wt[k0+2][stok + 32 ] = (double)wr1.z; wt[k0+3][stok + 32 ] = (double)wr1.w;
            wt[k0+0][stok + 64 ] = (double)wr2.x; wt[k0+1][stok + 64 ] = (double)wr2.y;
            wt[k0+2][stok + 64 ] = (double)wr2.z; wt[k0+3][stok + 64 ] = (double)wr2.w;
            wt[k0+0][stok + 96 ] = (double)wr3.x; wt[k0+1][stok + 96 ] = (double)wr3.y;
            wt[k0+2][stok + 96 ] = (double)wr3.z; wt[k0+3][stok + 96 ] = (double)wr3.w;
        }
        __syncthreads();
        if (c + 1 < NC) {
            const int off = (c + 1) * DK;
            xr  = *reinterpret_cast<const float4*>(xsrc + off);
            wr0 = *reinterpret_cast<const float4*>(wsrc[0] + off);
            wr1 = *reinterpret_cast<const float4*>(wsrc[1] + off);
            wr2 = *reinterpret_cast<const float4*>(wsrc[2] + off);
            wr3 = *reinterpret_cast<const float4*>(wsrc[3] + off);
        }
        #pragma unroll 4
        for (int k = 0; k < DK; ++k) {
            const double2_t xv0 = *reinterpret_cast<const double2_t*>(&xs[k][tg * 4]);
            const double2_t xv1 = *reinterpret_cast<const double2_t*>(&xs[k][tg * 4 + 2]);
            const double2_t w0  = *reinterpret_cast<const double2_t*>(&wt[k][2 * eg]);
            const double2_t w1  = *reinterpret_cast<const double2_t*>(&wt[k][64 + 2 * eg]);
            const double xvv[4] = {xv0.x, xv0.y, xv1.x, xv1.y};
            #pragma unroll
            for (int t = 0; t < 4; ++t) {
                acc[t][0] = fma(xvv[t], w0.x, acc[t][0]);
                acc[t][1] = fma(xvv[t], w0.y, acc[t][1]);
                acc[t][2] = fma(xvv[t], w1.x, acc[t][2]);
                acc[t][3] = fma(xvv[t], w1.y, acc[t][3]);
            }
        }
    }
    __syncthreads();
    #pragma unroll
    for (int t = 0; t < 4; ++t) {
        double2_t lo = {acc[t][0], acc[t][1]};
        double2_t hi = {acc[t][2], acc[t][3]};
        *reinterpret_cast<double2_t*>(&zbuf[tg * 4 + t][2 * eg])      = lo;
        *reinterpret_cast<double2_t*>(&zbuf[tg * 4 + t][64 + 2 * eg]) = hi;
    }
    __syncthreads();

    const int wid  = tid >> 6;
    const int lane = tid & 63;
    for (int tt = 0; tt < 8; ++tt) {
        const int tok = wid * 8 + tt;
        const size_t gtok = (size_t)tok0 + tok;
        const double logit = zbuf[tok][lane];
        const double noisy = zbuf[tok][EE + lane];
        const double zv = (double)noise_u[gtok * EE + lane] * softplus64(noisy)
                          + logit + (double)bias[lane];
        double zw = zv;
        bool   sel = false;
        double m0  = 0.0;
        #pragma unroll
        for (int it = 0; it < KK; ++it) {
            double v  = zw;
            int    ix = lane;
            #pragma unroll
            for (int off = 32; off > 0; off >>= 1) {
                const double ov = __shfl_xor(v, off, 64);
                const int    oi = __shfl_xor(ix, off, 64);
                if (ov > v || (ov == v && oi < ix)) { v = ov; ix = oi; }
            }
            if (it == 0) m0 = v;
            if (lane == ix) { sel = true; zw = -INFINITY; }
            if (lane == 0) out_idx[gtok * KK + it] = (float)ix;
        }
        const double ex = sel ? exp(zv - m0) : 0.0;
        double den = ex;
        #pragma unroll
        for (int off = 32; off > 0; off >>= 1) den += __shfl_xor(den, off, 64);
        out_probs[gtok * EE + lane] = (float)(ex / den);
    }
}

extern "C" void kernel_launch(void* const* d_in, const int* in_sizes, int n_in,
                              void* d_out, int out_size, void* d_ws, size_t ws_size,
                              hipStream_t stream)
{
    const float* x       = (const float*)d_in[0];
    const float* Wr      = (const float*)d_in[1];
    const float* Wn      = (const float*)d_in[2];
    const float* bias    = (const float*)d_in[3];
    const float* noise_u = (const float*)d_in[4];

    float* out       = (float*)d_out;
    float* out_probs = out;
    float* out_idx   = out + (size_t)TT_TOTAL * EE;
    float* out_bias  = out + (size_t)TT_TOTAL * EE + (size_t)TT_TOTAL * KK;

    const size_t zsplit = (size_t)TT_TOTAL * E2 * sizeof(float);  // 8 MiB
    const size_t extras = (size_t)(TT_TOTAL + 64) * sizeof(int);  // list + cnt

    int KS = 0;
    if      (ws_size >= 8 * zsplit + extras) KS = 8;
    else if (ws_size >= 4 * zsplit + extras) KS = 4;
    else if (ws_size >= 2 * zsplit + extras) KS = 2;

    if (KS > 0) {
        float* zp        = (float*)d_ws;
        int*   flag_list = (int*)((char*)d_ws + (size_t)KS * zsplit);
        int*   flag_cnt  = flag_list + TT_TOTAL;

        zero_kernel<<<1, 64, 0, stream>>>(flag_cnt);
        if (KS == 8) {
            gemmf32_kernel<8><<<128 * 8, 256, 0, stream>>>(x, Wr, Wn, zp);
            topkf_kernel<8><<<TT_TOTAL / 32, 256, 0, stream>>>(
                zp, bias, noise_u, out_probs, out_idx, flag_list, flag_cnt);
        } else if (KS == 4) {
            gemmf32_kernel<4><<<128 * 4, 256, 0, stream>>>(x, Wr, Wn, zp);
            topkf_kernel<4><<<TT_TOTAL / 32, 256, 0, stream>>>(
                zp, bias, noise_u, out_probs, out_idx, flag_list, flag_cnt);
        } else {
            gemmf32_kernel<2><<<128 * 2, 256, 0, stream>>>(x, Wr, Wn, zp);
            topkf_kernel<2><<<TT_TOTAL / 32, 256, 0, stream>>>(
                zp, bias, noise_u, out_probs, out_idx, flag_list, flag_cnt);
        }
        repair_kernel<<<256, 256, 0, stream>>>(x, Wr, Wn, bias, noise_u,
                                               out_probs, out_idx,
                                               flag_list, flag_cnt);
    } else {
        router_kernel<<<TT_TOTAL / 32, 256, 0, stream>>>(
            x, Wr, Wn, bias, noise_u, out_probs, out_idx);
    }
    bias_kernel<<<1, 64, 0, stream>>>(bias, out_bias);
}